// Round 14
// baseline (439.892 us; speedup 1.0000x reference)
//
#include <hip/hip_runtime.h>

// Soft-DTW (gamma=1), batched 64 x (1024 vs 1024, 2-D points).
//
// === R14: exact R11 skeleton (341us champion), ONE change: K=16 -> 32 ===
// R13 bundled prefetch+split+XK and regressed (390us) -- abandoned.
// R8 (K=8): 4032 cyc/epoch; R11 (K=16): 5720 cyc/epoch => per-epoch wall =
// F + m*K with F ~2300-4200 (handoff RT, poll, rescale, ring, barrier) and
// m ~95-211 cyc/step. K=32 halves F's per-step share: NGRP 143 -> 79.
// Register-math adjustments (mechanical, not protocol): wb[] eliminated
// (lane 63 publishes per-step: LDS ds_write / relaxed-agent store; same
// values, same pre-rescale off); rvc/vr_p merged into one vr[32] converted
// in place at epoch top. SLOTS 8->4 keeps workspace ~205 KB.
//
// Geometry: 256 blocks = 64 batches x PARTS=4 parts x WPB=4 waves (all 256
// CUs, 1 wave/SIMD -- the R12-measured cap). Global wave w = part*4+wl runs
// K diagonals behind wave w-1. One __syncthreads per epoch.
//
// Core (verified absmax 0.0 since R8): exp2-domain Z = 2^(off - R*log2e);
//   Z_d[i] = 2^(-D*log2e) * (Zdiag + Zup + Zleft)
// chain = add+add+mul (f64) + DPP shift + selects, zero transcendentals
// on-chain; per-wave exact power-of-2 rescale per epoch (DPP max-reduce,
// pure VALU); neighbor values converted by exact 2^(off-oin) two-stage
// factors; intra-block boundary via LDS parity ring (reader epoch g uses
// writer epoch g-1, parity (g^1)&1; overwrite 2 barriers later);
// cross-block via RELAXED agent-scope atomics (LLC-coherent, no cache
// maintenance -- the R10->R11 fix): writer stores K values per-step + off
// -> vmcnt(0) -> flag=g; reader prefetches raw at epoch-g bottom (need=g,
// poll + compiler barrier + relaxed loads), converts in place at epoch-g+1
// top. Writer-finished epochs (need > WLAST) zero-fill: those values feed
// only inactive cells (k2=0 -> zn=0). Final cell snapshotted at its own
// step (exact; rescales are powers of 2); R = (res_off - log2(res)) * ln2.

#define N 1024
#define PARTS 4
#define TPB 256
#define WPB 4                                  // waves per block
#define NW_G (PARTS * WPB)                     // 16 global waves
#define K 32                                   // diagonals per epoch
#define SLOTS 4                                // cross-block ring depth
#define NBND (PARTS - 1)                       // 3 boundaries per batch
// last wave w=15: d0_15(g) <= hi_15  ->  g <= (64*15+1084+K*15)/K
#define NGRP ((64 * (NW_G - 1) + 1084 + K * (NW_G - 1)) / K + 1)   // 79
#define L2E 1.442695040888963f
#define LN2D 0.6931471805599453

// workspace: vals[64][NBND][SLOTS][K+1] int64, then flags[64][NBND] int64
#define VALS_LL (64 * NBND * SLOTS * (K + 1))
#define WS_BYTES (VALS_LL * 8 + 64 * NBND * 8)

__device__ __forceinline__ float sqdist2(float2 a, float2 b) {
    float dx = a.x - b.x;
    float dy = a.y - b.y;
    return dx * dx + dy * dy;
}

// 64-bit DPP move (two 32-bit halves, same lane pattern; invalid lanes -> 0).
template <int CTRL>
__device__ __forceinline__ double dpp_movd(double src) {
    long long s = __double_as_longlong(src);
    int lo = __builtin_amdgcn_update_dpp(0, (int)(s & 0xffffffffLL),
                                         CTRL, 0xF, 0xF, false);
    int hi = __builtin_amdgcn_update_dpp(0, (int)(s >> 32),
                                         CTRL, 0xF, 0xF, false);
    return __longlong_as_double(((long long)hi << 32) | (unsigned int)lo);
}

template <int CTRL>
__device__ __forceinline__ int dpp_maxstep(int x) {
    int s = __builtin_amdgcn_update_dpp(0, x, CTRL, 0xF, 0xF, false);
    return max(x, s);
}

// Full 64-lane max of a nonneg int, pure VALU (no LDS); result wave-uniform.
__device__ __forceinline__ int wave_max_i(int x) {
    x = dpp_maxstep<0x111>(x);   // row_shr:1
    x = dpp_maxstep<0x112>(x);   // row_shr:2
    x = dpp_maxstep<0x114>(x);   // row_shr:4
    x = dpp_maxstep<0x118>(x);   // row_shr:8
    x = dpp_maxstep<0x142>(x);   // row_bcast15
    x = dpp_maxstep<0x143>(x);   // row_bcast31
    return __builtin_amdgcn_readlane(x, 63);
}

// exact 2^s as double for s in [-1022, 1023]
__device__ __forceinline__ double pow2d(int s) {
    return __longlong_as_double((long long)(1023 + s) << 52);
}

__global__ __launch_bounds__(TPB) void dtw_kernel(
    const float2* __restrict__ snake,
    const float2* __restrict__ contour,
    float* __restrict__ out,
    long long* __restrict__ wsv,
    long long* __restrict__ wsf)
{
    const int t    = threadIdx.x;
    const int lane = t & 63;
    const int wl   = t >> 6;                 // local wave 0..3
    const int part = blockIdx.x >> 6;        // part-major: writers first
    const int b    = blockIdx.x & 63;        // batch
    const int w    = part * WPB + wl;        // global wave 0..15
    const int i    = (w << 6) + lane;        // global DP row

    __shared__ double ringv[WPB][2][K];      // intra-block boundary ring
    __shared__ int    ringo[WPB][2];
    __shared__ float  initvals[3];           // R0[0], R1[0], R1[1]

    const float2* sg = snake   + (size_t)b * N;
    const float2* cg = contour + (size_t)b * N;
    const float2 sp = sg[i];                 // snake point: register-resident

    if (t < WPB * 2 * K) ((double*)ringv)[t] = 0.0;   // Z(INF) = 0 (256 slots)
    if (t < WPB * 2)     ((int*)ringo)[t] = 0;
    if (part == 0 && t == 0) {
        // Diagonals 0 and 1 (reference `init`):
        float2 s0 = sg[0], s1 = sg[1], c0 = cg[0], c1 = cg[1];
        float d00 = sqdist2(s0, c0);
        initvals[0] = d00;
        initvals[1] = sqdist2(s0, c1) + d00;
        initvals[2] = sqdist2(s1, c0) + d00;
    }
    __syncthreads();

    // Z-state entering the wave's first executed step (off = 0):
    double cur = 0.0, nb1 = 0.0, nb2 = 0.0;
    int off = 0;
    bool adopted = (w == 0);
    if (part == 0) {
        if (t == 0) {
            cur = (double)__builtin_amdgcn_exp2f(-L2E * initvals[1]);
        } else if (t == 1) {
            cur = (double)__builtin_amdgcn_exp2f(-L2E * initvals[2]);
            nb1 = (double)__builtin_amdgcn_exp2f(-L2E * initvals[1]);
            nb2 = (double)__builtin_amdgcn_exp2f(-L2E * initvals[0]);
        } else if (t == 2) {
            nb1 = (double)__builtin_amdgcn_exp2f(-L2E * initvals[2]);
        }
    }

    double res = 1.0;                        // final-cell snapshot (my row)
    int res_off = 0;

    const int lo = (w == 0) ? 2 : (64 * w - 1);   // -1 pre-step seeds nb1
    const int hi = 64 * w + 63 + (N - 1);
    // Writer (global wave w-1) last publishing epoch (valid for any K).
    const int WLAST = (w > 0) ? ((64 * (w - 1) + 1084) / K + (w - 1)) : 0;
    int d0 = 2 - K * w;

    double k2[K];                            // step factors (off-chain)
    double vr[K];                            // neighbor boundary values:
                                             //   wl>0: filled at top (LDS)
                                             //   wl=0: raw prefetch, converted
    #pragma unroll                           //         in place at top
    for (int k = 0; k < K; ++k) vr[k] = 0.0;
    int oin_p = 0;

    const bool lds_pub = (wl < WPB - 1);                  // wave-uniform
    const bool glb_pub = (wl == WPB - 1) && (part < PARTS - 1);

    const long long* vin =
        wsv + ((size_t)b * NBND + (part - 1)) * SLOTS * (K + 1);
    long long* vout =
        wsv + ((size_t)b * NBND + part) * SLOTS * (K + 1);
    const long long* fin = wsf + (b * NBND + (part - 1));
    long long* fout = wsf + (b * NBND + part);

    // Epoch-0 factors (prologue; cold loads acceptable once).
    #pragma unroll
    for (int k = 0; k < K; ++k) {
        const unsigned u = (unsigned)(d0 + k - i);
        float2 c = cg[u & (N - 1)];
        float dx = sp.x - c.x, dy = sp.y - c.y;
        float e = __builtin_amdgcn_exp2f((dx * dx + dy * dy) * (-L2E));
        k2[k] = (u < (unsigned)N) ? (double)e : 0.0;
    }

    for (int g = 0; g < NGRP; ++g) {
        const bool overlap = (d0 <= hi) && (d0 + (K - 1) >= lo);
        if (overlap) {
            long long* q = vout + (size_t)(g & (SLOTS - 1)) * (K + 1);

            if (w > 0) {
                int oin;
                if (wl > 0) {
                    const int p = (g ^ 1) & 1;
                    oin = ringo[wl - 1][p];                // all lanes (LDS)
                    if (!adopted) { off = oin; adopted = true; }
                    if (lane == 0) {
                        int dl = off - oin;
                        int c1 = min(max(dl, -1022), 1022);
                        int c2 = min(max(dl - c1, -1022), 1022);
                        double f1 = pow2d(c1), f2 = pow2d(c2);
                        const double* qq = &ringv[wl - 1][p][0];
                        #pragma unroll
                        for (int k = 0; k < K; ++k)
                            vr[k] = (qq[k] * f1) * f2;
                    }
                } else {
                    int tmp = (lane == 0) ? oin_p : 0;
                    oin = __builtin_amdgcn_readlane(tmp, 0);  // broadcast
                    if (!adopted) { off = oin; adopted = true; }
                    if (lane == 0) {
                        int dl = off - oin;
                        int c1 = min(max(dl, -1022), 1022);
                        int c2 = min(max(dl - c1, -1022), 1022);
                        double f1 = pow2d(c1), f2 = pow2d(c2);
                        #pragma unroll
                        for (int k = 0; k < K; ++k)        // raw -> converted
                            vr[k] = (vr[k] * f1) * f2;
                    }
                }
            }

            const int kres = (i + N - 1) - d0;   // step of my row's last cell

            // The chain: add+add+mul (f64) + DPP + selects per step.
            // Lane 63 publishes per-step (values at pre-rescale off).
            #pragma unroll
            for (int k = 0; k < K; ++k) {
                double zn = k2[k] * ((nb2 + nb1) + cur);
                if (k == kres) { res = zn; res_off = off; }
                cur = zn;
                if (lane == 63) {
                    if (lds_pub) {
                        ringv[wl][g & 1][k] = zn;
                    } else if (glb_pub) {
                        __hip_atomic_store(q + k, __double_as_longlong(zn),
                                           __ATOMIC_RELAXED,
                                           __HIP_MEMORY_SCOPE_AGENT);
                    }
                }
                double a  = dpp_movd<0x111>(zn);   // row_shr:1
                double bc = dpp_movd<0x142>(zn);   // row_bcast15
                double up = ((lane & 15) == 0) ? bc : a;
                nb2 = nb1;
                nb1 = (lane == 0) ? vr[k] : up;
            }

            // Boundary epilogue: offsets + flag (all pre-rescale, as R11).
            if (lane == 63) {
                if (lds_pub) {
                    ringo[wl][g & 1] = off;
                } else if (glb_pub) {
                    __hip_atomic_store(q + K, (long long)off,
                                       __ATOMIC_RELAXED,
                                       __HIP_MEMORY_SCOPE_AGENT);
                    asm volatile("s_waitcnt vmcnt(0)" ::: "memory");
                    __hip_atomic_store(fout, (long long)g, __ATOMIC_RELAXED,
                                       __HIP_MEMORY_SCOPE_AGENT);
                }
            }

            // Per-wave exact power-of-2 rescale (DPP max-reduce, no LDS).
            int e = (int)((__double_as_longlong(cur) >> 52) & 0x7FF);
            e = wave_max_i(e);
            if (e > 0) {
                int sh = 1023 - e;
                int c1 = min(max(sh, -1022), 1022);
                int c2 = min(max(sh - c1, -1022), 1022);
                double f1 = pow2d(c1), f2 = pow2d(c2);
                cur = (cur * f1) * f2;
                nb1 = (nb1 * f1) * f2;
                nb2 = (nb2 * f1) * f2;
                off += sh;
            }
        }

        d0 += K;

        // Epoch BOTTOM: next-epoch factors (loads + exp2, R11-style).
        #pragma unroll
        for (int k = 0; k < K; ++k) {
            const unsigned u = (unsigned)(d0 + k - i);
            float2 c = cg[u & (N - 1)];
            float dx = sp.x - c.x, dy = sp.y - c.y;
            float e = __builtin_amdgcn_exp2f((dx * dx + dy * dy) * (-L2E));
            k2[k] = (u < (unsigned)N) ? (double)e : 0.0;
        }

        // Cross-block PREFETCH for epoch g+1 (poll+read at epoch bottom ->
        // handoff latency hides under the barrier / epoch tail).
        if (wl == 0 && w > 0) {
            const bool nov = (d0 <= hi) && (d0 + (K - 1) >= lo);
            if (nov && lane == 0) {
                const int need = g;           // = (g+1) - 1
                if (need > WLAST) {
                    // Writer finished: values feed only inactive cells.
                    #pragma unroll
                    for (int k = 0; k < K; ++k) vr[k] = 0.0;
                    oin_p = off;              // zeros are offset-immune
                } else {
                    while (__hip_atomic_load(fin, __ATOMIC_RELAXED,
                                             __HIP_MEMORY_SCOPE_AGENT)
                           < (long long)need)
                        __builtin_amdgcn_s_sleep(2);
                    asm volatile("" ::: "memory");   // no hoist past poll
                    const long long* qq =
                        vin + (size_t)(need & (SLOTS - 1)) * (K + 1);
                    #pragma unroll
                    for (int k = 0; k < K; ++k)        // raw (converted @top)
                        vr[k] = __longlong_as_double(
                            __hip_atomic_load(qq + k, __ATOMIC_RELAXED,
                                              __HIP_MEMORY_SCOPE_AGENT));
                    oin_p = (int)__hip_atomic_load(qq + K, __ATOMIC_RELAXED,
                                                   __HIP_MEMORY_SCOPE_AGENT);
                }
            }
        }

        __syncthreads();
    }

    // Global row 1023 lives in part 3, t 255: res = Z of R[1023,1023].
    if (part == PARTS - 1 && t == TPB - 1) {
        double R = ((double)res_off - log2(res)) * LN2D;
        atomicAdd(out, (float)(R * (1.0 / 64.0)));
    }
}

extern "C" void kernel_launch(void* const* d_in, const int* in_sizes, int n_in,
                              void* d_out, int out_size, void* d_ws, size_t ws_size,
                              hipStream_t stream) {
    const float2* snake   = (const float2*)d_in[0];
    const float2* contour = (const float2*)d_in[1];
    float* out = (float*)d_out;
    // Harness re-poisons d_out to 0xAA before every timed launch.
    hipMemsetAsync(out, 0, sizeof(float), stream);
    // Cross-block flags must start at -1 (0xFF...) every launch.
    hipMemsetAsync(d_ws, 0xFF, WS_BYTES, stream);
    long long* wsv = (long long*)d_ws;
    long long* wsf = (long long*)((char*)d_ws + (size_t)VALS_LL * 8);
    dtw_kernel<<<PARTS * 64, TPB, 0, stream>>>(snake, contour, out, wsv, wsf);
}

// Round 15
// 369.832 us; speedup vs baseline: 1.1894x; 1.1894x over previous
//
#include <hip/hip_runtime.h>

// Soft-DTW (gamma=1), batched 64 x (1024 vs 1024, 2-D points).
//
// === R15: one block per batch, 2 rows/lane, 2 waves/SIMD, LDS-only ===
// Evidence chain: per-step wall ~360 cyc of which ~95 issue (R11/R14) =>
// ~265 cyc/step dependent-chain stall at 1 wave/SIMD; R12 proved 2 waves/
// SIMD hides almost all of it (2x work per CU at 1.16x time) but wasted
// half the CUs. At 64 rows/wave the device pins to 1 wave/SIMD (1024 waves
// on 1024 SIMDs). Fix: 2 ROWS PER LANE (lane owns rows 2l, 2l+1):
//  - hi cell's predecessors R[r_hi-1]@(d-1,d-2) are this lane's own
//    cur_lo/old_lo registers (no DPP); lo and hi cells are INDEPENDENT
//    within a step (hi uses pre-update lo) -> 2x ILP too.
//  - 8 waves x 128 rows per batch -> ONE block per batch (64 blocks x 512
//    threads) -> 8 waves / 4 SIMDs = 2 waves/SIMD on every active CU.
//  - ALL cross-block transport deleted (d_ws, atomics, poll, WLAST):
//    only the R2-verified LDS parity ring remains. 192 CUs idle -- fine:
//    the computation is chain-latency-bound, not throughput-bound.
//  - contour reuse: cell(d,r_hi) uses contour[d-r_hi] = contour[(d-1)-r_lo]
//    = previous k's lo load -> half the k2 loads.
//
// Core (verified absmax 0.0 since R8): exp2-domain Z = 2^(off - R*log2e);
//   Z_d[i] = 2^(-D*log2e) * (Zdiag + Zup + Zleft)
// Per-cell op order kept bit-identical: zn = k2 * ((nb2 + nb1) + cur) with
// the matching predecessors; zero transcendentals on-chain; per-wave exact
// power-of-2 rescale per epoch (DPP max-reduce, pure VALU) over all 5 state
// regs; neighbor values converted by exact 2^(off-oin) two-stage factors;
// wave w runs K=16 diagonals behind wave w-1; one __syncthreads per epoch;
// ring parity double-buffer (reader epoch g reads writer epoch g-1, parity
// (g^1)&1; overwrite 2 barriers later -> race-free). Inactive cells: k2=0
// -> zn=0 (pre-start/finished lanes zero out automatically, excluded from
// the rescale max). Final cell (row 1023, d=2046) snapshotted at its own
// step (exact; rescales are powers of 2); R = (res_off - log2(res)) * ln2.

#define N 1024
#define TPB 512
#define WPB 8                                  // waves per block = per batch
#define K 16                                   // diagonals per epoch
// last wave w=7: d0_7(g) = 2+K(g-7) <= 128*7+1150  ->  g <= 7 + 2044/K
#define NGRP ((128 * (WPB - 1) + 1148) / K + (WPB - 1) + 1)   // 135
#define L2E 1.442695040888963f
#define LN2D 0.6931471805599453

__device__ __forceinline__ float sqdist2(float2 a, float2 b) {
    float dx = a.x - b.x;
    float dy = a.y - b.y;
    return dx * dx + dy * dy;
}

// 64-bit DPP move (two 32-bit halves, same lane pattern; invalid lanes -> 0).
template <int CTRL>
__device__ __forceinline__ double dpp_movd(double src) {
    long long s = __double_as_longlong(src);
    int lo = __builtin_amdgcn_update_dpp(0, (int)(s & 0xffffffffLL),
                                         CTRL, 0xF, 0xF, false);
    int hi = __builtin_amdgcn_update_dpp(0, (int)(s >> 32),
                                         CTRL, 0xF, 0xF, false);
    return __longlong_as_double(((long long)hi << 32) | (unsigned int)lo);
}

template <int CTRL>
__device__ __forceinline__ int dpp_maxstep(int x) {
    int s = __builtin_amdgcn_update_dpp(0, x, CTRL, 0xF, 0xF, false);
    return max(x, s);
}

// Full 64-lane max of a nonneg int, pure VALU (no LDS); result wave-uniform.
__device__ __forceinline__ int wave_max_i(int x) {
    x = dpp_maxstep<0x111>(x);   // row_shr:1
    x = dpp_maxstep<0x112>(x);   // row_shr:2
    x = dpp_maxstep<0x114>(x);   // row_shr:4
    x = dpp_maxstep<0x118>(x);   // row_shr:8
    x = dpp_maxstep<0x142>(x);   // row_bcast15
    x = dpp_maxstep<0x143>(x);   // row_bcast31
    return __builtin_amdgcn_readlane(x, 63);
}

// exact 2^s as double for s in [-1022, 1023]
__device__ __forceinline__ double pow2d(int s) {
    return __longlong_as_double((long long)(1023 + s) << 52);
}

__global__ __launch_bounds__(TPB, 2) void dtw_kernel(
    const float2* __restrict__ snake,
    const float2* __restrict__ contour,
    float* __restrict__ out)
{
    const int t    = threadIdx.x;
    const int lane = t & 63;
    const int w    = t >> 6;                 // wave 0..7
    const int b    = blockIdx.x;             // batch
    const int il   = (w << 7) + 2 * lane;    // lo row
    const int ih   = il + 1;                 // hi row

    __shared__ double ringv[WPB][2][K];      // boundary ring (LDS only)
    __shared__ int    ringo[WPB][2];
    __shared__ float  initvals[3];           // R0[0], R1[0], R1[1]

    const float2* sg = snake   + (size_t)b * N;
    const float2* cg = contour + (size_t)b * N;
    const float2 sp_l = sg[il];              // snake points: registers
    const float2 sp_h = sg[ih];

    if (t < WPB * 2 * K) ((double*)ringv)[t] = 0.0;   // Z(INF) = 0
    if (t < WPB * 2)     ((int*)ringo)[t] = 0;
    if (t == 0) {
        // Diagonals 0 and 1 (reference `init`):
        float2 s0 = sg[0], s1 = sg[1], c0 = cg[0], c1 = cg[1];
        float d00 = sqdist2(s0, c0);
        initvals[0] = d00;
        initvals[1] = sqdist2(s0, c1) + d00;
        initvals[2] = sqdist2(s1, c0) + d00;
    }
    __syncthreads();

    // State entering d=2 (off = 0):
    //   cur_lo = Z_{d-1}[il], cur_hi = Z_{d-1}[ih], old_lo = Z_{d-2}[il],
    //   nbh1 = Z_{d-1}[il-1], nbh2 = Z_{d-2}[il-1]   (neighbor lane's hi row)
    double cur_lo = 0.0, cur_hi = 0.0, old_lo = 0.0;
    double nbh1 = 0.0, nbh2 = 0.0;
    int off = 0;
    bool adopted = (w == 0);
    if (t == 0) {            // rows 0,1: R1[0], R1[1], R0[0]
        cur_lo = (double)__builtin_amdgcn_exp2f(-L2E * initvals[1]);
        cur_hi = (double)__builtin_amdgcn_exp2f(-L2E * initvals[2]);
        old_lo = (double)__builtin_amdgcn_exp2f(-L2E * initvals[0]);
    } else if (t == 1) {     // row 2's left neighbor = row 1 at d=1
        nbh1 = (double)__builtin_amdgcn_exp2f(-L2E * initvals[2]);
    }

    double res = 1.0;                        // final-cell snapshot
    int res_off = 0;

    const int lo = (w == 0) ? 2 : (128 * w - 1);  // -1 pre-step seeds nbh1
    const int hi = 128 * w + 127 + (N - 1);       // 128w + 1150
    int d0 = 2 - K * w;

    double k2l[K], k2h[K], vr[K], wb[K];
    #pragma unroll
    for (int k = 0; k < K; ++k) vr[k] = 0.0;

    // Epoch-0 factors. Contour reuse: c_h(k) = c_l(k-1).
    {
        float2 cprev = cg[(unsigned)(d0 - 1 - il) & (N - 1)];
        #pragma unroll
        for (int k = 0; k < K; ++k) {
            const unsigned ul = (unsigned)(d0 + k - il);
            const unsigned uh = (unsigned)(d0 + k - ih);
            float2 cc = cg[ul & (N - 1)];
            float el = __builtin_amdgcn_exp2f(sqdist2(sp_l, cc) * (-L2E));
            float eh = __builtin_amdgcn_exp2f(sqdist2(sp_h, cprev) * (-L2E));
            k2l[k] = (ul < (unsigned)N) ? (double)el : 0.0;
            k2h[k] = (uh < (unsigned)N) ? (double)eh : 0.0;
            cprev = cc;
        }
    }

    for (int g = 0; g < NGRP; ++g) {
        const bool overlap = (d0 <= hi) && (d0 + (K - 1) >= lo);
        if (overlap) {
            if (w > 0) {
                const int p = (g ^ 1) & 1;
                int oin = ringo[w - 1][p];            // LDS broadcast
                if (!adopted) { off = oin; adopted = true; }
                if (lane == 0) {
                    int dl = off - oin;
                    int c1 = min(max(dl, -1022), 1022);
                    int c2 = min(max(dl - c1, -1022), 1022);
                    double f1 = pow2d(c1), f2 = pow2d(c2);
                    const double* q = &ringv[w - 1][p][0];
                    #pragma unroll
                    for (int k = 0; k < K; ++k)
                        vr[k] = (q[k] * f1) * f2;
                }
            }

            const int kres = (ih + N - 1) - d0;  // step of hi row's last cell

            // Chain: two INDEPENDENT cells per step (hi uses pre-update lo).
            // Per-cell op order bit-identical to R8-R14.
            #pragma unroll
            for (int k = 0; k < K; ++k) {
                double zn_h = k2h[k] * ((old_lo + cur_lo) + cur_hi);
                double zn_l = k2l[k] * ((nbh2 + nbh1) + cur_lo);
                if (k == kres) { res = zn_h; res_off = off; }
                wb[k] = zn_h;
                old_lo = cur_lo;
                cur_lo = zn_l;
                cur_hi = zn_h;
                double a  = dpp_movd<0x111>(zn_h);   // row_shr:1
                double bc = dpp_movd<0x142>(zn_h);   // row_bcast15
                double up = ((lane & 15) == 0) ? bc : a;
                nbh2 = nbh1;
                nbh1 = (lane == 0) ? vr[k] : up;
            }

            // Boundary publish (batched, pre-rescale off). Wave 7 has no
            // reader.
            if (lane == 63 && w < WPB - 1) {
                #pragma unroll
                for (int k = 0; k < K; ++k) ringv[w][g & 1][k] = wb[k];
                ringo[w][g & 1] = off;
            }

            // Per-wave exact power-of-2 rescale (DPP max-reduce, no LDS).
            int el = (int)((__double_as_longlong(cur_lo) >> 52) & 0x7FF);
            int eh = (int)((__double_as_longlong(cur_hi) >> 52) & 0x7FF);
            int e = wave_max_i(max(el, eh));
            if (e > 0) {
                int sh = 1023 - e;
                int c1 = min(max(sh, -1022), 1022);
                int c2 = min(max(sh - c1, -1022), 1022);
                double f1 = pow2d(c1), f2 = pow2d(c2);
                cur_lo = (cur_lo * f1) * f2;
                cur_hi = (cur_hi * f1) * f2;
                old_lo = (old_lo * f1) * f2;
                nbh1   = (nbh1   * f1) * f2;
                nbh2   = (nbh2   * f1) * f2;
                off += sh;
            }
        }

        d0 += K;

        // Epoch bottom: next-epoch factors (independent loads; latency
        // hidden by the co-resident wave at 2 waves/SIMD).
        {
            float2 cprev = cg[(unsigned)(d0 - 1 - il) & (N - 1)];
            #pragma unroll
            for (int k = 0; k < K; ++k) {
                const unsigned ul = (unsigned)(d0 + k - il);
                const unsigned uh = (unsigned)(d0 + k - ih);
                float2 cc = cg[ul & (N - 1)];
                float el2 = __builtin_amdgcn_exp2f(sqdist2(sp_l, cc) * (-L2E));
                float eh2 = __builtin_amdgcn_exp2f(sqdist2(sp_h, cprev) * (-L2E));
                k2l[k] = (ul < (unsigned)N) ? (double)el2 : 0.0;
                k2h[k] = (uh < (unsigned)N) ? (double)eh2 : 0.0;
                cprev = cc;
            }
        }

        __syncthreads();
    }

    // Row 1023 = hi row of wave 7, lane 63 (t = 511): res = Z of
    // R[1023,1023] at res_off (exact snapshot; rescales are powers of 2).
    if (t == TPB - 1) {
        double R = ((double)res_off - log2(res)) * LN2D;
        atomicAdd(out, (float)(R * (1.0 / 64.0)));
    }
}

extern "C" void kernel_launch(void* const* d_in, const int* in_sizes, int n_in,
                              void* d_out, int out_size, void* d_ws, size_t ws_size,
                              hipStream_t stream) {
    const float2* snake   = (const float2*)d_in[0];
    const float2* contour = (const float2*)d_in[1];
    float* out = (float*)d_out;
    // Harness re-poisons d_out to 0xAA before every timed launch.
    hipMemsetAsync(out, 0, sizeof(float), stream);
    dtw_kernel<<<64, TPB, 0, stream>>>(snake, contour, out);
}

// Round 16
// 366.839 us; speedup vs baseline: 1.1991x; 1.0082x over previous
//
#include <hip/hip_runtime.h>

// Soft-DTW (gamma=1), batched 64 x (1024 vs 1024, 2-D points).
//
// === R16: R15 structure, arrays ACTUALLY in registers ===
// R15 counters exposed the session-long bottleneck: VGPR_Count=68 but the
// kernel's unrolled arrays (k2l/k2h/vr/wb = 64 doubles = 128 VGPRs) exceed
// the budget -> the compiler spilled them to SCRATCH. Every chain step was
// doing scratch loads (k2[k], vr[k]) + stores (wb[k]) with ~120-200cyc
// latency ON the serial dependency chain. This explains the invariant
// ~260-300 cyc/step stall across R11-R15 (transport/geometry changes never
// touched it) and stall scaling with K. Fixes (R15 logic byte-identical):
//  1. k2l/k2h stored as f32 (computed as f32 anyway; widening at use is
//     EXACT -> bit-identical results). 64 -> 32 VGPRs.
//  2. wb[] eliminated: lane 63 publishes zn_h per-step into the LDS ring
//     (exec-masked, off-chain). -32 VGPRs.
//  Total ~105 VGPRs -> fits 2 waves/SIMD (256 cap) with margin.
//
// Geometry (R15): one block per batch, 64 blocks x 512 threads (8 waves,
// 2 waves/SIMD); lane owns rows 2l (lo) and 2l+1 (hi); hi cell's
// predecessors are this lane's own cur_lo/old_lo (no DPP); lo+hi cells are
// independent per step (2x ILP). LDS-only boundary transport.
//
// Core (verified absmax 0.0 since R8): exp2-domain Z = 2^(off - R*log2e);
//   Z_d[i] = 2^(-D*log2e) * (Zdiag + Zup + Zleft)
// Per-cell op order bit-identical: zn = k2 * ((nb2 + nb1) + cur); zero
// transcendentals on-chain; per-wave exact power-of-2 rescale per epoch
// (DPP max-reduce, pure VALU) over all 5 state regs; lane-0 neighbor
// values converted by exact 2^(off-oin) two-stage factors; wave w runs
// K=16 diagonals behind wave w-1; one __syncthreads per epoch; ring parity
// double-buffer (reader epoch g reads writer epoch g-1, parity (g^1)&1;
// overwrite 2 barriers later). Inactive cells: k2=0 -> zn=0 (pre-start /
// finished lanes auto-zero, excluded from the rescale max). Final cell
// (row 1023, d=2046) snapshotted at its own step (exact; rescales are
// powers of 2); R = (res_off - log2(res)) * ln2.

#define N 1024
#define TPB 512
#define WPB 8                                  // waves per block = per batch
#define K 16                                   // diagonals per epoch
#define NGRP ((128 * (WPB - 1) + 1148) / K + (WPB - 1) + 1)   // 135
#define L2E 1.442695040888963f
#define LN2D 0.6931471805599453

__device__ __forceinline__ float sqdist2(float2 a, float2 b) {
    float dx = a.x - b.x;
    float dy = a.y - b.y;
    return dx * dx + dy * dy;
}

// 64-bit DPP move (two 32-bit halves, same lane pattern; invalid lanes -> 0).
template <int CTRL>
__device__ __forceinline__ double dpp_movd(double src) {
    long long s = __double_as_longlong(src);
    int lo = __builtin_amdgcn_update_dpp(0, (int)(s & 0xffffffffLL),
                                         CTRL, 0xF, 0xF, false);
    int hi = __builtin_amdgcn_update_dpp(0, (int)(s >> 32),
                                         CTRL, 0xF, 0xF, false);
    return __longlong_as_double(((long long)hi << 32) | (unsigned int)lo);
}

template <int CTRL>
__device__ __forceinline__ int dpp_maxstep(int x) {
    int s = __builtin_amdgcn_update_dpp(0, x, CTRL, 0xF, 0xF, false);
    return max(x, s);
}

// Full 64-lane max of a nonneg int, pure VALU (no LDS); result wave-uniform.
__device__ __forceinline__ int wave_max_i(int x) {
    x = dpp_maxstep<0x111>(x);   // row_shr:1
    x = dpp_maxstep<0x112>(x);   // row_shr:2
    x = dpp_maxstep<0x114>(x);   // row_shr:4
    x = dpp_maxstep<0x118>(x);   // row_shr:8
    x = dpp_maxstep<0x142>(x);   // row_bcast15
    x = dpp_maxstep<0x143>(x);   // row_bcast31
    return __builtin_amdgcn_readlane(x, 63);
}

// exact 2^s as double for s in [-1022, 1023]
__device__ __forceinline__ double pow2d(int s) {
    return __longlong_as_double((long long)(1023 + s) << 52);
}

__global__ __launch_bounds__(TPB, 2) void dtw_kernel(
    const float2* __restrict__ snake,
    const float2* __restrict__ contour,
    float* __restrict__ out)
{
    const int t    = threadIdx.x;
    const int lane = t & 63;
    const int w    = t >> 6;                 // wave 0..7
    const int b    = blockIdx.x;             // batch
    const int il   = (w << 7) + 2 * lane;    // lo row
    const int ih   = il + 1;                 // hi row

    __shared__ double ringv[WPB][2][K];      // boundary ring (LDS only)
    __shared__ int    ringo[WPB][2];
    __shared__ float  initvals[3];           // R0[0], R1[0], R1[1]

    const float2* sg = snake   + (size_t)b * N;
    const float2* cg = contour + (size_t)b * N;
    const float2 sp_l = sg[il];              // snake points: registers
    const float2 sp_h = sg[ih];

    if (t < WPB * 2 * K) ((double*)ringv)[t] = 0.0;   // Z(INF) = 0
    if (t < WPB * 2)     ((int*)ringo)[t] = 0;
    if (t == 0) {
        // Diagonals 0 and 1 (reference `init`):
        float2 s0 = sg[0], s1 = sg[1], c0 = cg[0], c1 = cg[1];
        float d00 = sqdist2(s0, c0);
        initvals[0] = d00;
        initvals[1] = sqdist2(s0, c1) + d00;
        initvals[2] = sqdist2(s1, c0) + d00;
    }
    __syncthreads();

    // State entering d=2 (off = 0):
    //   cur_lo = Z_{d-1}[il], cur_hi = Z_{d-1}[ih], old_lo = Z_{d-2}[il],
    //   nbh1 = Z_{d-1}[il-1], nbh2 = Z_{d-2}[il-1]  (neighbor lane's hi row)
    double cur_lo = 0.0, cur_hi = 0.0, old_lo = 0.0;
    double nbh1 = 0.0, nbh2 = 0.0;
    int off = 0;
    bool adopted = (w == 0);
    if (t == 0) {            // rows 0,1: R1[0], R1[1], R0[0]
        cur_lo = (double)__builtin_amdgcn_exp2f(-L2E * initvals[1]);
        cur_hi = (double)__builtin_amdgcn_exp2f(-L2E * initvals[2]);
        old_lo = (double)__builtin_amdgcn_exp2f(-L2E * initvals[0]);
    } else if (t == 1) {     // row 2's left neighbor = row 1 at d=1
        nbh1 = (double)__builtin_amdgcn_exp2f(-L2E * initvals[2]);
    }

    double res = 1.0;                        // final-cell snapshot
    int res_off = 0;

    const int lo = (w == 0) ? 2 : (128 * w - 1);  // -1 pre-step seeds nbh1
    const int hi = 128 * w + 127 + (N - 1);       // 128w + 1150
    int d0 = 2 - K * w;

    float k2l[K], k2h[K];                    // step factors, f32 (16+16 VGPR)
    double vr[K];                            // converted ring (lane 0 only)
    #pragma unroll
    for (int k = 0; k < K; ++k) vr[k] = 0.0;

    // Epoch-0 factors. Contour reuse: c_h(k) = c_l(k-1).
    {
        float2 cprev = cg[(unsigned)(d0 - 1 - il) & (N - 1)];
        #pragma unroll
        for (int k = 0; k < K; ++k) {
            const unsigned ul = (unsigned)(d0 + k - il);
            const unsigned uh = (unsigned)(d0 + k - ih);
            float2 cc = cg[ul & (N - 1)];
            float el = __builtin_amdgcn_exp2f(sqdist2(sp_l, cc) * (-L2E));
            float eh = __builtin_amdgcn_exp2f(sqdist2(sp_h, cprev) * (-L2E));
            k2l[k] = (ul < (unsigned)N) ? el : 0.0f;
            k2h[k] = (uh < (unsigned)N) ? eh : 0.0f;
            cprev = cc;
        }
    }

    for (int g = 0; g < NGRP; ++g) {
        const bool overlap = (d0 <= hi) && (d0 + (K - 1) >= lo);
        if (overlap) {
            if (w > 0) {
                const int p = (g ^ 1) & 1;
                int oin = ringo[w - 1][p];            // LDS broadcast
                if (!adopted) { off = oin; adopted = true; }
                if (lane == 0) {
                    int dl = off - oin;
                    int c1 = min(max(dl, -1022), 1022);
                    int c2 = min(max(dl - c1, -1022), 1022);
                    double f1 = pow2d(c1), f2 = pow2d(c2);
                    const double* q = &ringv[w - 1][p][0];
                    #pragma unroll
                    for (int k = 0; k < K; ++k)
                        vr[k] = (q[k] * f1) * f2;
                }
            }

            const int kres = (ih + N - 1) - d0;  // step of hi row's last cell
            const bool pub = (lane == 63) && (w < WPB - 1);

            // Chain: two INDEPENDENT cells per step (hi uses pre-update lo).
            // f32->f64 widening of k2 is exact (bit-identical to f64 stores).
            #pragma unroll
            for (int k = 0; k < K; ++k) {
                double zn_h = (double)k2h[k] * ((old_lo + cur_lo) + cur_hi);
                double zn_l = (double)k2l[k] * ((nbh2 + nbh1) + cur_lo);
                if (k == kres) { res = zn_h; res_off = off; }
                if (pub) ringv[w][g & 1][k] = zn_h;   // off-chain LDS store
                old_lo = cur_lo;
                cur_lo = zn_l;
                cur_hi = zn_h;
                double a  = dpp_movd<0x111>(zn_h);   // row_shr:1
                double bc = dpp_movd<0x142>(zn_h);   // row_bcast15
                double up = ((lane & 15) == 0) ? bc : a;
                nbh2 = nbh1;
                nbh1 = (lane == 0) ? vr[k] : up;
            }

            if (pub) ringo[w][g & 1] = off;          // pre-rescale offset

            // Per-wave exact power-of-2 rescale (DPP max-reduce, no LDS).
            int el = (int)((__double_as_longlong(cur_lo) >> 52) & 0x7FF);
            int eh = (int)((__double_as_longlong(cur_hi) >> 52) & 0x7FF);
            int e = wave_max_i(max(el, eh));
            if (e > 0) {
                int sh = 1023 - e;
                int c1 = min(max(sh, -1022), 1022);
                int c2 = min(max(sh - c1, -1022), 1022);
                double f1 = pow2d(c1), f2 = pow2d(c2);
                cur_lo = (cur_lo * f1) * f2;
                cur_hi = (cur_hi * f1) * f2;
                old_lo = (old_lo * f1) * f2;
                nbh1   = (nbh1   * f1) * f2;
                nbh2   = (nbh2   * f1) * f2;
                off += sh;
            }
        }

        d0 += K;

        // Epoch bottom: next-epoch factors (latency hidden by the
        // co-resident wave at 2 waves/SIMD).
        {
            float2 cprev = cg[(unsigned)(d0 - 1 - il) & (N - 1)];
            #pragma unroll
            for (int k = 0; k < K; ++k) {
                const unsigned ul = (unsigned)(d0 + k - il);
                const unsigned uh = (unsigned)(d0 + k - ih);
                float2 cc = cg[ul & (N - 1)];
                float el2 = __builtin_amdgcn_exp2f(sqdist2(sp_l, cc) * (-L2E));
                float eh2 = __builtin_amdgcn_exp2f(sqdist2(sp_h, cprev) * (-L2E));
                k2l[k] = (ul < (unsigned)N) ? el2 : 0.0f;
                k2h[k] = (uh < (unsigned)N) ? eh2 : 0.0f;
                cprev = cc;
            }
        }

        __syncthreads();
    }

    // Row 1023 = hi row of wave 7, lane 63 (t = 511): res = Z of
    // R[1023,1023] at res_off (exact snapshot; rescales are powers of 2).
    if (t == TPB - 1) {
        double R = ((double)res_off - log2(res)) * LN2D;
        atomicAdd(out, (float)(R * (1.0 / 64.0)));
    }
}

extern "C" void kernel_launch(void* const* d_in, const int* in_sizes, int n_in,
                              void* d_out, int out_size, void* d_ws, size_t ws_size,
                              hipStream_t stream) {
    const float2* snake   = (const float2*)d_in[0];
    const float2* contour = (const float2*)d_in[1];
    float* out = (float*)d_out;
    // Harness re-poisons d_out to 0xAA before every timed launch.
    hipMemsetAsync(out, 0, sizeof(float), stream);
    dtw_kernel<<<64, TPB, 0, stream>>>(snake, contour, out);
}

// Round 17
// 364.668 us; speedup vs baseline: 1.2063x; 1.0060x over previous
//
#include <hip/hip_runtime.h>

// Soft-DTW (gamma=1), batched 64 x (1024 vs 1024, 2-D points).
//
// === R17: R16 + asm-volatile pins to defeat compiler prefetch-sinking ===
// R16 evidence triple: VGPR_Count=56 (arrays can't fit), WRITE_SIZE=2KB (no
// scratch traffic), wall unchanged (~355 cyc/step) => the compiler SINKS the
// epoch-bottom k2 prefetch across the barrier into the next epoch's chain,
// and sinks the lane-0 ring-read+conversion into the chain loop -- putting
// an L1-load / lgkmcnt wait ON the serial chain once per step. The software
// pipeline has been silently undone since R11 (the invariant ~30% stall).
// Fix: asm volatile("" :: "v"(x)) pins after each prefetch block. LLVM
// cannot sink computations feeding an asm-volatile past it, nor across the
// side-effecting __syncthreads. Pins are numeric no-ops -> absmax 0.0.
//  - vr[16] pinned after the epoch-top conversion (one lgkm wait up front,
//    not 16 on-chain).
//  - k2l/k2h pinned right before the barrier (loads+exp2 execute in epoch
//    g, consumed in g+1 from registers).
// Confirming signal: VGPR_Count must jump to >=100 (cap 256 @ 2 waves/SIMD).
//
// Geometry (R15/R16): one block per batch, 64 blocks x 512 threads (8 waves,
// 2 waves/SIMD); lane owns rows 2l (lo) and 2l+1 (hi); hi cell's
// predecessors are this lane's own cur_lo/old_lo (no DPP); lo+hi cells
// independent per step (2x ILP). LDS-only boundary transport.
//
// Core (verified absmax 0.0 since R8): exp2-domain Z = 2^(off - R*log2e);
//   Z_d[i] = 2^(-D*log2e) * (Zdiag + Zup + Zleft)
// Per-cell op order bit-identical: zn = k2 * ((nb2 + nb1) + cur); zero
// transcendentals on-chain; per-wave exact power-of-2 rescale per epoch
// (DPP max-reduce, pure VALU); lane-0 neighbor values converted by exact
// 2^(off-oin) two-stage factors; wave w runs K=16 diagonals behind wave
// w-1; one __syncthreads per epoch; ring parity double-buffer (reader epoch
// g reads writer epoch g-1, parity (g^1)&1; overwrite 2 barriers later).
// Inactive cells: k2=0 -> zn=0. Final cell (row 1023, d=2046) snapshotted
// at its own step (exact); R = (res_off - log2(res)) * ln2.

#define N 1024
#define TPB 512
#define WPB 8                                  // waves per block = per batch
#define K 16                                   // diagonals per epoch
#define NGRP ((128 * (WPB - 1) + 1148) / K + (WPB - 1) + 1)   // 135
#define L2E 1.442695040888963f
#define LN2D 0.6931471805599453

#define PIN_D(x) asm volatile("" :: "v"(x))
#define PIN_F(x) asm volatile("" :: "v"(x))

__device__ __forceinline__ float sqdist2(float2 a, float2 b) {
    float dx = a.x - b.x;
    float dy = a.y - b.y;
    return dx * dx + dy * dy;
}

// 64-bit DPP move (two 32-bit halves, same lane pattern; invalid lanes -> 0).
template <int CTRL>
__device__ __forceinline__ double dpp_movd(double src) {
    long long s = __double_as_longlong(src);
    int lo = __builtin_amdgcn_update_dpp(0, (int)(s & 0xffffffffLL),
                                         CTRL, 0xF, 0xF, false);
    int hi = __builtin_amdgcn_update_dpp(0, (int)(s >> 32),
                                         CTRL, 0xF, 0xF, false);
    return __longlong_as_double(((long long)hi << 32) | (unsigned int)lo);
}

template <int CTRL>
__device__ __forceinline__ int dpp_maxstep(int x) {
    int s = __builtin_amdgcn_update_dpp(0, x, CTRL, 0xF, 0xF, false);
    return max(x, s);
}

// Full 64-lane max of a nonneg int, pure VALU (no LDS); result wave-uniform.
__device__ __forceinline__ int wave_max_i(int x) {
    x = dpp_maxstep<0x111>(x);   // row_shr:1
    x = dpp_maxstep<0x112>(x);   // row_shr:2
    x = dpp_maxstep<0x114>(x);   // row_shr:4
    x = dpp_maxstep<0x118>(x);   // row_shr:8
    x = dpp_maxstep<0x142>(x);   // row_bcast15
    x = dpp_maxstep<0x143>(x);   // row_bcast31
    return __builtin_amdgcn_readlane(x, 63);
}

// exact 2^s as double for s in [-1022, 1023]
__device__ __forceinline__ double pow2d(int s) {
    return __longlong_as_double((long long)(1023 + s) << 52);
}

__global__ __launch_bounds__(TPB, 2) void dtw_kernel(
    const float2* __restrict__ snake,
    const float2* __restrict__ contour,
    float* __restrict__ out)
{
    const int t    = threadIdx.x;
    const int lane = t & 63;
    const int w    = t >> 6;                 // wave 0..7
    const int b    = blockIdx.x;             // batch
    const int il   = (w << 7) + 2 * lane;    // lo row
    const int ih   = il + 1;                 // hi row

    __shared__ double ringv[WPB][2][K];      // boundary ring (LDS only)
    __shared__ int    ringo[WPB][2];
    __shared__ float  initvals[3];           // R0[0], R1[0], R1[1]

    const float2* sg = snake   + (size_t)b * N;
    const float2* cg = contour + (size_t)b * N;
    const float2 sp_l = sg[il];              // snake points: registers
    const float2 sp_h = sg[ih];

    if (t < WPB * 2 * K) ((double*)ringv)[t] = 0.0;   // Z(INF) = 0
    if (t < WPB * 2)     ((int*)ringo)[t] = 0;
    if (t == 0) {
        // Diagonals 0 and 1 (reference `init`):
        float2 s0 = sg[0], s1 = sg[1], c0 = cg[0], c1 = cg[1];
        float d00 = sqdist2(s0, c0);
        initvals[0] = d00;
        initvals[1] = sqdist2(s0, c1) + d00;
        initvals[2] = sqdist2(s1, c0) + d00;
    }
    __syncthreads();

    // State entering d=2 (off = 0):
    //   cur_lo = Z_{d-1}[il], cur_hi = Z_{d-1}[ih], old_lo = Z_{d-2}[il],
    //   nbh1 = Z_{d-1}[il-1], nbh2 = Z_{d-2}[il-1]  (neighbor lane's hi row)
    double cur_lo = 0.0, cur_hi = 0.0, old_lo = 0.0;
    double nbh1 = 0.0, nbh2 = 0.0;
    int off = 0;
    bool adopted = (w == 0);
    if (t == 0) {            // rows 0,1: R1[0], R1[1], R0[0]
        cur_lo = (double)__builtin_amdgcn_exp2f(-L2E * initvals[1]);
        cur_hi = (double)__builtin_amdgcn_exp2f(-L2E * initvals[2]);
        old_lo = (double)__builtin_amdgcn_exp2f(-L2E * initvals[0]);
    } else if (t == 1) {     // row 2's left neighbor = row 1 at d=1
        nbh1 = (double)__builtin_amdgcn_exp2f(-L2E * initvals[2]);
    }

    double res = 1.0;                        // final-cell snapshot
    int res_off = 0;

    const int lo = (w == 0) ? 2 : (128 * w - 1);  // -1 pre-step seeds nbh1
    const int hi = 128 * w + 127 + (N - 1);       // 128w + 1150
    int d0 = 2 - K * w;

    float k2l[K], k2h[K];                    // step factors, f32
    double vr[K];                            // converted ring (lane 0 only)
    #pragma unroll
    for (int k = 0; k < K; ++k) vr[k] = 0.0;

    // Epoch-0 factors. Contour reuse: c_h(k) = c_l(k-1).
    {
        float2 cprev = cg[(unsigned)(d0 - 1 - il) & (N - 1)];
        #pragma unroll
        for (int k = 0; k < K; ++k) {
            const unsigned ul = (unsigned)(d0 + k - il);
            const unsigned uh = (unsigned)(d0 + k - ih);
            float2 cc = cg[ul & (N - 1)];
            float el = __builtin_amdgcn_exp2f(sqdist2(sp_l, cc) * (-L2E));
            float eh = __builtin_amdgcn_exp2f(sqdist2(sp_h, cprev) * (-L2E));
            k2l[k] = (ul < (unsigned)N) ? el : 0.0f;
            k2h[k] = (uh < (unsigned)N) ? eh : 0.0f;
            cprev = cc;
        }
    }

    for (int g = 0; g < NGRP; ++g) {
        const bool overlap = (d0 <= hi) && (d0 + (K - 1) >= lo);
        if (overlap) {
            if (w > 0) {
                const int p = (g ^ 1) & 1;
                int oin = ringo[w - 1][p];            // LDS broadcast
                if (!adopted) { off = oin; adopted = true; }
                if (lane == 0) {
                    int dl = off - oin;
                    int c1 = min(max(dl, -1022), 1022);
                    int c2 = min(max(dl - c1, -1022), 1022);
                    double f1 = pow2d(c1), f2 = pow2d(c2);
                    const double* q = &ringv[w - 1][p][0];
                    #pragma unroll
                    for (int k = 0; k < K; ++k)
                        vr[k] = (q[k] * f1) * f2;
                }
                // PIN: force ring read + conversion to complete HERE (one
                // lgkm wait up front), not sunk into the chain loop.
                #pragma unroll
                for (int k = 0; k < K; ++k) PIN_D(vr[k]);
            }

            const int kres = (ih + N - 1) - d0;  // step of hi row's last cell
            const bool pub = (lane == 63) && (w < WPB - 1);

            // Chain: two INDEPENDENT cells per step (hi uses pre-update lo).
            // f32->f64 widening of k2 is exact (bit-identical).
            #pragma unroll
            for (int k = 0; k < K; ++k) {
                double zn_h = (double)k2h[k] * ((old_lo + cur_lo) + cur_hi);
                double zn_l = (double)k2l[k] * ((nbh2 + nbh1) + cur_lo);
                if (k == kres) { res = zn_h; res_off = off; }
                if (pub) ringv[w][g & 1][k] = zn_h;   // off-chain LDS store
                old_lo = cur_lo;
                cur_lo = zn_l;
                cur_hi = zn_h;
                double a  = dpp_movd<0x111>(zn_h);   // row_shr:1
                double bc = dpp_movd<0x142>(zn_h);   // row_bcast15
                double up = ((lane & 15) == 0) ? bc : a;
                nbh2 = nbh1;
                nbh1 = (lane == 0) ? vr[k] : up;
            }

            if (pub) ringo[w][g & 1] = off;          // pre-rescale offset

            // Per-wave exact power-of-2 rescale (DPP max-reduce, no LDS).
            int el = (int)((__double_as_longlong(cur_lo) >> 52) & 0x7FF);
            int eh = (int)((__double_as_longlong(cur_hi) >> 52) & 0x7FF);
            int e = wave_max_i(max(el, eh));
            if (e > 0) {
                int sh = 1023 - e;
                int c1 = min(max(sh, -1022), 1022);
                int c2 = min(max(sh - c1, -1022), 1022);
                double f1 = pow2d(c1), f2 = pow2d(c2);
                cur_lo = (cur_lo * f1) * f2;
                cur_hi = (cur_hi * f1) * f2;
                old_lo = (old_lo * f1) * f2;
                nbh1   = (nbh1   * f1) * f2;
                nbh2   = (nbh2   * f1) * f2;
                off += sh;
            }
        }

        d0 += K;

        // Epoch bottom: next-epoch factors.
        {
            float2 cprev = cg[(unsigned)(d0 - 1 - il) & (N - 1)];
            #pragma unroll
            for (int k = 0; k < K; ++k) {
                const unsigned ul = (unsigned)(d0 + k - il);
                const unsigned uh = (unsigned)(d0 + k - ih);
                float2 cc = cg[ul & (N - 1)];
                float el2 = __builtin_amdgcn_exp2f(sqdist2(sp_l, cc) * (-L2E));
                float eh2 = __builtin_amdgcn_exp2f(sqdist2(sp_h, cprev) * (-L2E));
                k2l[k] = (ul < (unsigned)N) ? el2 : 0.0f;
                k2h[k] = (uh < (unsigned)N) ? eh2 : 0.0f;
                cprev = cc;
            }
        }
        // PIN: force loads + exp2 to execute BEFORE the barrier (true
        // prefetch; consumed next epoch from registers).
        #pragma unroll
        for (int k = 0; k < K; ++k) { PIN_F(k2l[k]); PIN_F(k2h[k]); }

        __syncthreads();
    }

    // Row 1023 = hi row of wave 7, lane 63 (t = 511): res = Z of
    // R[1023,1023] at res_off (exact snapshot; rescales are powers of 2).
    if (t == TPB - 1) {
        double R = ((double)res_off - log2(res)) * LN2D;
        atomicAdd(out, (float)(R * (1.0 / 64.0)));
    }
}

extern "C" void kernel_launch(void* const* d_in, const int* in_sizes, int n_in,
                              void* d_out, int out_size, void* d_ws, size_t ws_size,
                              hipStream_t stream) {
    const float2* snake   = (const float2*)d_in[0];
    const float2* contour = (const float2*)d_in[1];
    float* out = (float*)d_out;
    // Harness re-poisons d_out to 0xAA before every timed launch.
    hipMemsetAsync(out, 0, sizeof(float), stream);
    dtw_kernel<<<64, TPB, 0, stream>>>(snake, contour, out);
}